// Round 9
// baseline (3566.232 us; speedup 1.0000x reference)
//
#include <hip/hip_runtime.h>
#include <math.h>

typedef __attribute__((ext_vector_type(8))) short bf16x8;
typedef __attribute__((ext_vector_type(4))) float f32x4;
typedef __attribute__((ext_vector_type(4))) unsigned short us4;

__device__ inline unsigned short f2bf(float f){
  unsigned u = __float_as_uint(f);
  u += 0x7fff + ((u>>16)&1);
  return (unsigned short)(u>>16);
}

// offset arg ALWAYS 0 (round-4 failure: imm-offset semantics ambiguous).
__device__ __forceinline__ void gload16(const unsigned short* g, char* l){
  __builtin_amdgcn_global_load_lds(
      (const __attribute__((address_space(1))) unsigned int*)g,
      (__attribute__((address_space(3))) unsigned int*)l, 16, 0, 0);
}

// ---------- feat NCHW fp32 -> featT NHWC bf16 (padded width Wp=W+2) ----------
__global__ __launch_bounds__(256) void k_trans(const float* __restrict__ feat,
    unsigned short* __restrict__ ft, int H, int W, int Wp, int y_begin,
    int slot_base, int RBf)
{
  int t = threadIdx.x;
  int lane = t & 63, wv = t >> 6;
  int x = blockIdx.x*64 + lane;
  int y = y_begin + blockIdx.y;
  int b = blockIdx.z;
  int slot = slot_base + blockIdx.y;
  if (x >= W) return;
  const float* fb = feat + ((size_t)(b*256)*H + y)*W + x;
  unsigned short* dst = ft + (((size_t)b*RBf + slot)*Wp + x + 1)*256;
  #pragma unroll 4
  for (int i=0;i<16;i++){
    int c0 = wv*4 + i*16;
    float v0 = fb[(size_t)(c0+0)*H*W];
    float v1 = fb[(size_t)(c0+1)*H*W];
    float v2 = fb[(size_t)(c0+2)*H*W];
    float v3 = fb[(size_t)(c0+3)*H*W];
    us4 o = { f2bf(v0), f2bf(v1), f2bf(v2), f2bf(v3) };
    *(us4*)(dst + c0) = o;
  }
}

// ---------- zero helpers ----------
__global__ __launch_bounds__(256) void k_zrow(unsigned short* __restrict__ buf,
    long bStr, int Wp, int slot0, int nslots)
{
  long i = ((long)blockIdx.x*256 + threadIdx.x)*8;
  long per_b = (long)nslots*Wp*256;
  if (i >= 4*per_b) return;
  int b = (int)(i / per_b); long r = i % per_b;
  unsigned short* d = buf + (size_t)b*bStr + (size_t)slot0*Wp*256 + r;
  us4 z = {0,0,0,0};
  *(us4*)d = z; *(us4*)(d+4) = z;
}

__global__ __launch_bounds__(256) void k_zcol(unsigned short* __restrict__ buf,
    int Wp, int RB, int W)
{
  long i = ((long)blockIdx.x*256 + threadIdx.x)*8;
  long tot = (long)4*RB*2*256;
  if (i >= tot) return;
  long u = i/8; int q = (int)(u & 31); int side = (int)((u>>5)&1);
  long bs = u>>6; int slot = (int)(bs % RB); int b = (int)(bs / RB);
  unsigned short* d = buf + (((size_t)b*RB + slot)*Wp + (side? W+1 : 0))*256 + q*8;
  us4 z = {0,0,0,0};
  *(us4*)d = z; *(us4*)(d+4) = z;
}

// ---------- weight repacks (layouts verified in round 2) ----------
__global__ __launch_bounds__(256) void k_repack_conv(const float* __restrict__ w,
    const float* __restrict__ g, const float* __restrict__ v,
    unsigned short* __restrict__ wf)
{
  int t = blockIdx.x*256 + threadIdx.x;
  if (t >= 4*256*256) return;
  int ci = t & 255, co = (t>>8) & 255, l = t>>16;
  float s = g[l*256+co] * rsqrtf(v[l*256+co] + 1e-5f);
  const float* wp = w + (size_t)t*9;
  int cb = co>>4, kc = ci>>5;
  int lane = ((ci>>3)&3)*16 + (co&15);
  int e = ci&7;
  size_t base = (((size_t)(l*16+cb)*8 + kc)*9)*512 + (size_t)lane*8 + e;
  #pragma unroll
  for (int tap=0;tap<9;tap++)
    wf[base + (size_t)tap*512] = f2bf(wp[tap]*s);
}

__global__ __launch_bounds__(256) void k_repack_adapt(const float* __restrict__ w,
    unsigned short* __restrict__ wf)
{
  int t = blockIdx.x*256 + threadIdx.x;
  if (t >= 4*256*32) return;
  int o = t & 31, co = (t>>5)&255, l = t>>13;
  int ci0 = o*8;
  const float* wp = w + ((size_t)(l*256+co)*256 + ci0);
  int cb = co>>4, kc = o>>2, lane = (o&3)*16 + (co&15);
  unsigned short* dst = wf + (((size_t)(l*16+cb)*8 + kc)*64 + lane)*8;
  unsigned short tmp[8];
  #pragma unroll
  for (int e=0;e<8;e++) tmp[e] = f2bf(wp[e]);
  *(us4*)dst = *(us4*)tmp; *(us4*)(dst+4) = *(us4*)(tmp+4);
}

__global__ __launch_bounds__(192) void k_repack_pred(const float* __restrict__ w,
    unsigned short* __restrict__ wf)
{
  int t = blockIdx.x*192 + threadIdx.x;
  if (t >= 4*48*32) return;
  int o = t & 31, co = (t>>5)%48, l = t/1536;
  int ci0 = o*8, f = co>>4, kc = o>>2, lane = (o&3)*16 + (co&15);
  unsigned short* dst = wf + ((((size_t)l*8 + kc)*3 + f)*64 + lane)*8;
  #pragma unroll
  for (int e=0;e<8;e++){
    float val = (co<45) ? w[((size_t)(l*45+co)*256 + ci0 + e)] : 0.f;
    dst[e] = f2bf(val);
  }
}

__global__ __launch_bounds__(256) void k_bias(const float* __restrict__ b,
    const float* __restrict__ g, const float* __restrict__ be,
    const float* __restrict__ m, const float* __restrict__ v,
    float* __restrict__ out)
{
  int t = blockIdx.x*256 + threadIdx.x;
  if (t >= 1024) return;
  float s = g[t]*rsqrtf(v[t]+1e-5f);
  out[t] = (b[t]-m[t])*s + be[t];
}

// ---------- MFMA conv: 256co x 2rows x 64px per block, 4 waves, cf=8 ----------
// wave = 128co (8 cf) x 64px x 1 row. acc = 128 AGPR; launch_bounds(256,2)
// caps arch+acc regs at 256 so 2 waves/SIMD stay resident (gfx950 unified
// file: R8's 148+128=276 regs silently dropped to 1 wave/SIMD -> 11% occ).
// Double-buffered LDS, stage(next)->compute(cur)->__syncthreads per kc.
template<int TAPS, bool RELU>
__global__ __launch_bounds__(256,2) void k_conv5(
    const unsigned short* __restrict__ in, const unsigned short* __restrict__ wf,
    const float* __restrict__ bias, unsigned short* __restrict__ outb,
    int W, int Wp, int y_begin, int y_end, int in_row0, int RBin,
    int out_row0, int RBout)
{
  constexpr bool T9    = (TAPS==9);
  constexpr int ROWS   = T9 ? 4 : 2;       // staged input rows
  constexpr int PXS    = T9 ? 72 : 64;     // staged px (reads use <=66)
  constexpr int RSTR   = PXS*64;           // LDS bytes per staged row
  constexpr int BUFB   = ROWS*RSTR;        // 18432 / 8192
  constexpr int NCHK   = BUFB/1024;        // 18 / 8
  constexpr int NFULL  = NCHK/4;           // 4 / 2 (chunks all 4 waves load)
  constexpr int NTAIL  = NCHK - NFULL*4;   // 2 / 0 (chunks waves w<NTAIL load)
  constexpr int CPW    = NFULL + (NTAIL?1:0);
  constexpr int PERROW = PXS*4;            // 16B slots per row
  __shared__ __align__(1024) char lds[2*BUFB];

  int tid = threadIdx.x, lane = tid&63, w = tid>>6;
  int l15 = lane&15, g4 = lane>>4;
  int rw = w & 1, hw = w >> 1;
  int x0 = blockIdx.x*64;
  int y0 = y_begin + 2*blockIdx.y;
  int b  = blockIdx.z;

  size_t rowEl = (size_t)Wp*256;
  const unsigned short* gb;
  if (T9) gb = in + ((size_t)b*RBin + (y0-1-in_row0))*rowEl + (size_t)x0*256;
  else    gb = in + ((size_t)b*RBin + (y0  -in_row0))*rowEl + (size_t)(x0+1)*256;

  // per-lane staging offsets (int) from rolling base gb; wave-uniform LDS offs
  int Poff[CPW], Coff[CPW];
  #pragma unroll
  for (int i=0;i<CPW;i++){
    int c = (i<NFULL) ? (4*i + w) : (4*NFULL + w);
    int s = c*64 + lane;
    int r = s / PERROW;
    int rem = s - r*PERROW;
    int px = rem>>2, sq = rem&3;
    int slot = sq ^ (px&3);
    Poff[i] = r*(int)rowEl + px*256 + slot*8;
    Coff[i] = c*1024;
  }

  // per-lane swizzled LDS read offsets (row rw folded in; ky via immediate)
  int vb[T9?12:4];
  if constexpr (T9){
    #pragma unroll
    for (int kx=0;kx<3;kx++)
      #pragma unroll
      for (int pf=0;pf<4;pf++){
        int px = pf*16 + l15 + kx;
        vb[kx*4+pf] = rw*RSTR + px*64 + ((g4 ^ (px&3))<<4);
      }
  } else {
    #pragma unroll
    for (int pf=0;pf<4;pf++){
      int px = pf*16 + l15;
      vb[pf] = rw*RSTR + px*64 + ((g4 ^ (px&3))<<4);
    }
  }

  const unsigned short* wA = wf + (size_t)(hw*8)*(8*TAPS*512) + (size_t)lane*8;

  f32x4 acc[8][4];
  #pragma unroll
  for (int i=0;i<8;i++)
    #pragma unroll
    for (int j=0;j<4;j++) acc[i][j] = (f32x4){0.f,0.f,0.f,0.f};

  // stage current kc into buffer at byte offset jb; advance base one kc (64 B)
  const unsigned short* gbk = gb;
  auto stage = [&](int jb){
    #pragma unroll
    for (int i=0;i<NFULL;i++) gload16(gbk + Poff[i], (char*)&lds[0] + jb + Coff[i]);
    if constexpr (NTAIL > 0){
      if (w < NTAIL) gload16(gbk + Poff[NFULL], (char*)&lds[0] + jb + Coff[NFULL]);
    }
    gbk += 32;
  };

#define LOADB(G, BV) { constexpr int ky=(G)/3, kx=(G)%3; \
  _Pragma("unroll") \
  for (int pf=0;pf<4;pf++) BV[pf] = *(const bf16x8*)(base + ky*RSTR + vb[kx*4+pf]); }

#define LOADA(G, AV) { \
  _Pragma("unroll") \
  for (int cf=0;cf<8;cf++) AV[cf] = *(const bf16x8*)(wk + (size_t)cf*(8*TAPS*512) + (G)*512); }

#define MM(AV, BV) { \
  _Pragma("unroll") for (int cf=0;cf<8;cf++) \
  _Pragma("unroll") for (int pf=0;pf<4;pf++) \
    acc[cf][pf] = __builtin_amdgcn_mfma_f32_16x16x32_bf16(AV[cf], BV[pf], acc[cf][pf], 0,0,0); }

  auto compute = [&](int kc, const char* base){
    const unsigned short* wk = wA + (size_t)kc*(TAPS*512);
    bf16x8 A[8], B0[4], B1[4];
    if constexpr (T9){
      LOADB(0,B0)
      LOADB(1,B1) LOADA(0,A) MM(A,B0)
      LOADB(2,B0) LOADA(1,A) MM(A,B1)
      LOADB(3,B1) LOADA(2,A) MM(A,B0)
      LOADB(4,B0) LOADA(3,A) MM(A,B1)
      LOADB(5,B1) LOADA(4,A) MM(A,B0)
      LOADB(6,B0) LOADA(5,A) MM(A,B1)
      LOADB(7,B1) LOADA(6,A) MM(A,B0)
      LOADB(8,B0) LOADA(7,A) MM(A,B1)
      LOADA(8,A) MM(A,B0)
    } else {
      LOADB(0,B0) LOADA(0,A) MM(A,B0)
    }
  };

  // prologue: stage kc=0 into buf0
  stage(0);
  __syncthreads();
  #pragma unroll 1
  for (int kt=0; kt<4; ++kt){
    stage(BUFB);                          // odd-kc loads fly under compute
    compute(2*kt, (const char*)&lds[0]);
    __syncthreads();                      // drains staging + guards buf reuse
    if (kt < 3) stage(0);                 // even-kc prefetch
    compute(2*kt+1, (const char*)&lds[0] + BUFB);
    __syncthreads();
  }
#undef LOADB
#undef LOADA
#undef MM

  // epilogue: bias (+BN folded) + ReLU, bf16 NHWC store
  int y = y0 + rw;
  if (y < y_end){
    int oslot = y - out_row0;
    unsigned short* ob = outb + ((size_t)b*RBout + oslot)*rowEl + 256; // +1 pad col
    #pragma unroll
    for (int cf=0; cf<8; ++cf){
      int co0 = hw*128 + cf*16 + g4*4;
      f32x4 bb = *(const f32x4*)(bias + co0);
      #pragma unroll
      for (int pf=0; pf<4; ++pf){
        int x = x0 + pf*16 + l15;
        if (x < W){
          float v0 = acc[cf][pf][0]+bb[0], v1 = acc[cf][pf][1]+bb[1];
          float v2 = acc[cf][pf][2]+bb[2], v3 = acc[cf][pf][3]+bb[3];
          if (RELU){ v0=fmaxf(v0,0.f); v1=fmaxf(v1,0.f); v2=fmaxf(v2,0.f); v3=fmaxf(v3,0.f); }
          us4 o = { f2bf(v0), f2bf(v1), f2bf(v2), f2bf(v3) };
          *(us4*)(ob + (size_t)x*256 + co0) = o;
        }
      }
    }
  }
}

// ---------- pred MFMA: NHWC bf16 -> sectioned NCHW fp32 out ----------
__global__ __launch_bounds__(256) void k_pred_mfma(
    const unsigned short* __restrict__ in, const unsigned short* __restrict__ wfP,
    const float* __restrict__ bp, float* __restrict__ outl,
    int H, int W, int Wp, int y_begin, int in_row0, int RBin)
{
  __shared__ __align__(16) unsigned short Xs[64][40];
  int tid = threadIdx.x;
  int lane = tid&63, w = tid>>6;
  int l15 = lane&15, g4 = lane>>4;
  int x0 = blockIdx.x*64;
  int y = y_begin + blockIdx.y;
  int b = blockIdx.z;
  int slot = y - in_row0;
  const unsigned short* inb = in + (((size_t)b*RBin + slot)*Wp + 1)*256;

  f32x4 acc[3];
  #pragma unroll
  for (int f=0;f<3;f++) acc[f] = (f32x4){0.f,0.f,0.f,0.f};

  for (int kc=0;kc<8;kc++){
    {
      int px = tid>>2, qq = tid&3;
      int xg = x0+px;
      us4 v0={0,0,0,0}, v1={0,0,0,0};
      if (xg < W){
        const unsigned short* src = inb + (size_t)xg*256 + kc*32 + qq*8;
        v0 = *(const us4*)src; v1 = *(const us4*)(src+4);
      }
      unsigned short* d = &Xs[px][qq*8];
      *(us4*)d = v0; *(us4*)(d+4) = v1;
    }
    __syncthreads();
    bf16x8 Bf = *(const bf16x8*)&Xs[w*16 + l15][g4*8];
    #pragma unroll
    for (int f=0;f<3;f++){
      bf16x8 Af = *(const bf16x8*)(wfP + (((size_t)kc*3 + f)*64 + lane)*8);
      acc[f] = __builtin_amdgcn_mfma_f32_16x16x32_bf16(Af, Bf, acc[f], 0,0,0);
    }
    __syncthreads();
  }
  size_t S = (size_t)H*W;
  int px = x0 + w*16 + l15;
  if (px >= W) return;
  #pragma unroll
  for (int f=0;f<3;f++){
    #pragma unroll
    for (int r=0;r<4;r++){
      int co = f*16 + g4*4 + r;
      if (co < 45){
        float val = acc[f][r] + bp[co];
        int a_idx = co/15, c = co%15;
        int cum,c0,n;
        if (c<4)       {cum=0;c0=0;n=4;}
        else if (c==4) {cum=4;c0=4;n=1;}
        else if (c<10) {cum=5;c0=5;n=5;}
        else if (c<14) {cum=10;c0=10;n=4;}
        else           {cum=14;c0=14;n=1;}
        if (c==4) val = 1.f/(1.f+expf(-val));
        else if (c==14) val = (val>20.f? val : log1pf(expf(val))) + 1.f;
        size_t chan = ((size_t)(12*cum) + (size_t)((b*3+a_idx)*n + (c-c0)))*S;
        outl[chan + (size_t)y*W + px] = val;
      }
    }
  }
}

// ---------- host ----------
extern "C" void kernel_launch(void* const* d_in, const int* in_sizes, int n_in,
                              void* d_out, int out_size, void* d_ws, size_t ws_size,
                              hipStream_t stream)
{
  static const int Hs[4] = {192,96,48,24};
  static const int Wd[4] = {320,160,80,40};
  const float* feat[4] = {(const float*)d_in[0],(const float*)d_in[1],
                          (const float*)d_in[2],(const float*)d_in[3]};
  const float* adapt_w = (const float*)d_in[4];
  const float* adapt_b = (const float*)d_in[5];
  const float* w1 = (const float*)d_in[6];  const float* b1 = (const float*)d_in[7];
  const float* g1 = (const float*)d_in[8];  const float* be1= (const float*)d_in[9];
  const float* m1 = (const float*)d_in[10]; const float* v1 = (const float*)d_in[11];
  const float* w2 = (const float*)d_in[12]; const float* b2 = (const float*)d_in[13];
  const float* g2 = (const float*)d_in[14]; const float* be2= (const float*)d_in[15];
  const float* m2 = (const float*)d_in[16]; const float* v2 = (const float*)d_in[17];
  const float* wp = (const float*)d_in[18]; const float* bp = (const float*)d_in[19];
  float* out = (float*)d_out;

  char* base = (char*)d_ws;
  size_t off = 0;
  auto alloc = [&](size_t bytes)->char*{
    char* p = base + off; off = (off + bytes + 255) & ~(size_t)255; return p; };

  const size_t WF3_L = (size_t)16*8*9*512;
  const size_t WFA_L = (size_t)16*8*512;
  const size_t WFP_L = (size_t)8*3*512;
  unsigned short* wf1 = (unsigned short*)alloc(4*WF3_L*2);
  unsigned short* wf2 = (unsigned short*)alloc(4*WF3_L*2);
  unsigned short* wfA = (unsigned short*)alloc(4*WFA_L*2);
  unsigned short* wfP = (unsigned short*)alloc(4*WFP_L*2);
  float* biasc1 = (float*)alloc(1024*4);
  float* biasc2 = (float*)alloc(1024*4);
  char*  bufbase = base + off;
  size_t rem = (ws_size > off + 65536) ? (ws_size - off - 65536) : 0;

  k_repack_conv <<<dim3(1024), dim3(256), 0, stream>>>(w1, g1, v1, wf1);
  k_repack_conv <<<dim3(1024), dim3(256), 0, stream>>>(w2, g2, v2, wf2);
  k_repack_adapt<<<dim3(128),  dim3(256), 0, stream>>>(adapt_w, wfA);
  k_repack_pred <<<dim3(32),   dim3(192), 0, stream>>>(wp, wfP);
  k_bias<<<dim3(4), dim3(256), 0, stream>>>(b1, g1, be1, m1, v1, biasc1);
  k_bias<<<dim3(4), dim3(256), 0, stream>>>(b2, g2, be2, m2, v2, biasc2);

  size_t out_off = 0;
  for (int l=0;l<4;l++){
    int H = Hs[l], W = Wd[l], Wp = W + 2;
    size_t S = (size_t)H*W;
    size_t rowEl = (size_t)Wp*256;            // elements per slot-row (1 batch)
    long slotsAvail = (long)(rem / (rowEl*2));
    long Rl = (slotsAvail - 64) / 12;
    int R = (int)(Rl < 2 ? 2 : (Rl > H ? (long)H : Rl));
    int RBf = R + 4, RB1 = R + 2;
    unsigned short* featT = (unsigned short*)bufbase;      // also conv2 output
    unsigned short* buf0  = featT + ((size_t)4*RBf + 8)*rowEl;
    unsigned short* buf1  = buf0  + ((size_t)4*RBf + 8)*rowEl;
    int nPxT = (W + 63) / 64;
    long zcGrid0 = ((long)4*RBf*2*256 + 2047)/2048;
    long zcGrid1 = ((long)4*RB1*2*256 + 2047)/2048;
    k_zcol<<<dim3((unsigned)zcGrid0), dim3(256), 0, stream>>>(buf0, Wp, RBf, W);
    k_zcol<<<dim3((unsigned)zcGrid1), dim3(256), 0, stream>>>(buf1, Wp, RB1, W);

    for (int r0 = 0; r0 < H; r0 += R){
      int r1 = (r0 + R < H) ? (r0 + R) : H;
      int Rc = r1 - r0;
      int ya0 = (r0-2 < 0) ? 0 : r0-2;
      int ya1 = (r1+2 > H) ? H : r1+2;
      int yb0 = (r0-1 < 0) ? 0 : r0-1;
      int yb1 = (r1+1 > H) ? H : r1+1;

      if (r0 == 0){
        long zg = ((long)4*2*Wp*256 + 2047)/2048;
        k_zrow<<<dim3((unsigned)zg), dim3(256), 0, stream>>>(buf0, (long)RBf*Wp*256, Wp, 0, 2);
        long zg1 = ((long)4*1*Wp*256 + 2047)/2048;
        k_zrow<<<dim3((unsigned)zg1), dim3(256), 0, stream>>>(buf1, (long)RB1*Wp*256, Wp, 0, 1);
      }
      if (r1 == H){
        long zg = ((long)4*2*Wp*256 + 2047)/2048;
        k_zrow<<<dim3((unsigned)zg), dim3(256), 0, stream>>>(buf0, (long)RBf*Wp*256, Wp, Rc+2, 2);
        long zg1 = ((long)4*1*Wp*256 + 2047)/2048;
        k_zrow<<<dim3((unsigned)zg1), dim3(256), 0, stream>>>(buf1, (long)RB1*Wp*256, Wp, Rc+1, 1);
      }

      k_trans<<<dim3(nPxT, ya1-ya0, 4), dim3(256), 0, stream>>>(
          feat[l], featT, H, W, Wp, ya0, ya0-(r0-2), RBf);

      // adapt: featT -> buf0, rows [ya0, ya1)
      k_conv5<1,false><<<dim3(nPxT, (ya1-ya0+1)/2, 4), dim3(256), 0, stream>>>(
          featT, wfA + (size_t)l*WFA_L, adapt_b + l*256, buf0,
          W, Wp, ya0, ya1, r0-2, RBf, r0-2, RBf);

      // conv1: buf0 -> buf1, rows [yb0, yb1)
      k_conv5<9,true><<<dim3(nPxT, (yb1-yb0+1)/2, 4), dim3(256), 0, stream>>>(
          buf0, wf1 + (size_t)l*WF3_L, biasc1 + l*256, buf1,
          W, Wp, yb0, yb1, r0-2, RBf, r0-1, RB1);

      // conv2: buf1 -> featT, rows [r0, r1)
      k_conv5<9,true><<<dim3(nPxT, (Rc+1)/2, 4), dim3(256), 0, stream>>>(
          buf1, wf2 + (size_t)l*WF3_L, biasc2 + l*256, featT,
          W, Wp, r0, r1, r0-1, RB1, r0, RBf);

      k_pred_mfma<<<dim3(nPxT, Rc, 4), dim3(256), 0, stream>>>(
          featT, wfP + (size_t)l*WFP_L, bp + l*45, out + out_off,
          H, W, Wp, r0, r0, RBf);
    }
    out_off += (size_t)4*45*S;
  }
}

// Round 10
// 1593.764 us; speedup vs baseline: 2.2376x; 2.2376x over previous
//
#include <hip/hip_runtime.h>
#include <math.h>

typedef __attribute__((ext_vector_type(8))) short bf16x8;
typedef __attribute__((ext_vector_type(4))) float f32x4;
typedef __attribute__((ext_vector_type(4))) unsigned short us4;

__device__ inline unsigned short f2bf(float f){
  unsigned u = __float_as_uint(f);
  u += 0x7fff + ((u>>16)&1);
  return (unsigned short)(u>>16);
}

// offset arg ALWAYS 0 (round-4 failure: imm-offset semantics ambiguous).
__device__ __forceinline__ void gload16(const unsigned short* g, char* l){
  __builtin_amdgcn_global_load_lds(
      (const __attribute__((address_space(1))) unsigned int*)g,
      (__attribute__((address_space(3))) unsigned int*)l, 16, 0, 0);
}

// ---------- feat NCHW fp32 -> featT NHWC bf16 (padded width Wp=W+2) ----------
__global__ __launch_bounds__(256) void k_trans(const float* __restrict__ feat,
    unsigned short* __restrict__ ft, int H, int W, int Wp, int y_begin,
    int slot_base, int RBf)
{
  int t = threadIdx.x;
  int lane = t & 63, wv = t >> 6;
  int x = blockIdx.x*64 + lane;
  int y = y_begin + blockIdx.y;
  int b = blockIdx.z;
  int slot = slot_base + blockIdx.y;
  if (x >= W) return;
  const float* fb = feat + ((size_t)(b*256)*H + y)*W + x;
  unsigned short* dst = ft + (((size_t)b*RBf + slot)*Wp + x + 1)*256;
  #pragma unroll 4
  for (int i=0;i<16;i++){
    int c0 = wv*4 + i*16;
    float v0 = fb[(size_t)(c0+0)*H*W];
    float v1 = fb[(size_t)(c0+1)*H*W];
    float v2 = fb[(size_t)(c0+2)*H*W];
    float v3 = fb[(size_t)(c0+3)*H*W];
    us4 o = { f2bf(v0), f2bf(v1), f2bf(v2), f2bf(v3) };
    *(us4*)(dst + c0) = o;
  }
}

// ---------- zero helpers ----------
__global__ __launch_bounds__(256) void k_zrow(unsigned short* __restrict__ buf,
    long bStr, int Wp, int slot0, int nslots)
{
  long i = ((long)blockIdx.x*256 + threadIdx.x)*8;
  long per_b = (long)nslots*Wp*256;
  if (i >= 4*per_b) return;
  int b = (int)(i / per_b); long r = i % per_b;
  unsigned short* d = buf + (size_t)b*bStr + (size_t)slot0*Wp*256 + r;
  us4 z = {0,0,0,0};
  *(us4*)d = z; *(us4*)(d+4) = z;
}

__global__ __launch_bounds__(256) void k_zcol(unsigned short* __restrict__ buf,
    int Wp, int RB, int W)
{
  long i = ((long)blockIdx.x*256 + threadIdx.x)*8;
  long tot = (long)4*RB*2*256;
  if (i >= tot) return;
  long u = i/8; int q = (int)(u & 31); int side = (int)((u>>5)&1);
  long bs = u>>6; int slot = (int)(bs % RB); int b = (int)(bs / RB);
  unsigned short* d = buf + (((size_t)b*RB + slot)*Wp + (side? W+1 : 0))*256 + q*8;
  us4 z = {0,0,0,0};
  *(us4*)d = z; *(us4*)(d+4) = z;
}

// ---------- weight repacks (layouts verified in round 2) ----------
__global__ __launch_bounds__(256) void k_repack_conv(const float* __restrict__ w,
    const float* __restrict__ g, const float* __restrict__ v,
    unsigned short* __restrict__ wf)
{
  int t = blockIdx.x*256 + threadIdx.x;
  if (t >= 4*256*256) return;
  int ci = t & 255, co = (t>>8) & 255, l = t>>16;
  float s = g[l*256+co] * rsqrtf(v[l*256+co] + 1e-5f);
  const float* wp = w + (size_t)t*9;
  int cb = co>>4, kc = ci>>5;
  int lane = ((ci>>3)&3)*16 + (co&15);
  int e = ci&7;
  size_t base = (((size_t)(l*16+cb)*8 + kc)*9)*512 + (size_t)lane*8 + e;
  #pragma unroll
  for (int tap=0;tap<9;tap++)
    wf[base + (size_t)tap*512] = f2bf(wp[tap]*s);
}

__global__ __launch_bounds__(256) void k_repack_adapt(const float* __restrict__ w,
    unsigned short* __restrict__ wf)
{
  int t = blockIdx.x*256 + threadIdx.x;
  if (t >= 4*256*32) return;
  int o = t & 31, co = (t>>5)&255, l = t>>13;
  int ci0 = o*8;
  const float* wp = w + ((size_t)(l*256+co)*256 + ci0);
  int cb = co>>4, kc = o>>2, lane = (o&3)*16 + (co&15);
  unsigned short* dst = wf + (((size_t)(l*16+cb)*8 + kc)*64 + lane)*8;
  unsigned short tmp[8];
  #pragma unroll
  for (int e=0;e<8;e++) tmp[e] = f2bf(wp[e]);
  *(us4*)dst = *(us4*)tmp; *(us4*)(dst+4) = *(us4*)(tmp+4);
}

__global__ __launch_bounds__(192) void k_repack_pred(const float* __restrict__ w,
    unsigned short* __restrict__ wf)
{
  int t = blockIdx.x*192 + threadIdx.x;
  if (t >= 4*48*32) return;
  int o = t & 31, co = (t>>5)%48, l = t/1536;
  int ci0 = o*8, f = co>>4, kc = o>>2, lane = (o&3)*16 + (co&15);
  unsigned short* dst = wf + ((((size_t)l*8 + kc)*3 + f)*64 + lane)*8;
  #pragma unroll
  for (int e=0;e<8;e++){
    float val = (co<45) ? w[((size_t)(l*45+co)*256 + ci0 + e)] : 0.f;
    dst[e] = f2bf(val);
  }
}

__global__ __launch_bounds__(256) void k_bias(const float* __restrict__ b,
    const float* __restrict__ g, const float* __restrict__ be,
    const float* __restrict__ m, const float* __restrict__ v,
    float* __restrict__ out)
{
  int t = blockIdx.x*256 + threadIdx.x;
  if (t >= 1024) return;
  float s = g[t]*rsqrtf(v[t]+1e-5f);
  out[t] = (b[t]-m[t])*s + be[t];
}

// ---------- MFMA conv: 256co x 2rows x 64px per block, 4 waves ----------
// wave = 64co (cf=4) x 64px x BOTH rows (acc0/acc1). Each weight fragment is
// read by exactly ONE wave (no row duplication): A-L2 traffic per MFMA =
// 128 B -> util cap ~52% (R8's rw-dup layout measured saturated at its 26%
// cap). Double-buffered LDS, stage(next)->compute(cur)->__syncthreads per kc.
template<int TAPS, bool RELU>
__global__ __launch_bounds__(256,2) void k_conv5(
    const unsigned short* __restrict__ in, const unsigned short* __restrict__ wf,
    const float* __restrict__ bias, unsigned short* __restrict__ outb,
    int W, int Wp, int y_begin, int y_end, int in_row0, int RBin,
    int out_row0, int RBout)
{
  constexpr bool T9    = (TAPS==9);
  constexpr int ROWS   = T9 ? 4 : 2;       // staged input rows
  constexpr int PXS    = T9 ? 72 : 64;     // staged px (reads use <=66)
  constexpr int RSTR   = PXS*64;           // LDS bytes per staged row
  constexpr int BUFB   = ROWS*RSTR;        // 18432 / 8192
  constexpr int NCHK   = BUFB/1024;        // 18 / 8
  constexpr int NFULL  = NCHK/4;           // 4 / 2 (chunks all 4 waves load)
  constexpr int NTAIL  = NCHK - NFULL*4;   // 2 / 0 (chunks waves w<NTAIL load)
  constexpr int CPW    = NFULL + (NTAIL?1:0);
  constexpr int PERROW = PXS*4;            // 16B slots per row
  __shared__ __align__(1024) char lds[2*BUFB];

  int tid = threadIdx.x, lane = tid&63, w = tid>>6;
  int l15 = lane&15, g4 = lane>>4;
  int x0 = blockIdx.x*64;
  int y0 = y_begin + 2*blockIdx.y;
  int b  = blockIdx.z;

  size_t rowEl = (size_t)Wp*256;
  const unsigned short* gb;
  if (T9) gb = in + ((size_t)b*RBin + (y0-1-in_row0))*rowEl + (size_t)x0*256;
  else    gb = in + ((size_t)b*RBin + (y0  -in_row0))*rowEl + (size_t)(x0+1)*256;

  // per-lane staging offsets (int) from rolling base; wave-uniform LDS offs
  int Poff[CPW], Coff[CPW];
  #pragma unroll
  for (int i=0;i<CPW;i++){
    int c = (i<NFULL) ? (4*i + w) : (4*NFULL + w);
    int s = c*64 + lane;
    int r = s / PERROW;
    int rem = s - r*PERROW;
    int px = rem>>2, sq = rem&3;
    int slot = sq ^ (px&3);
    Poff[i] = r*(int)rowEl + px*256 + slot*8;
    Coff[i] = c*1024;
  }

  // per-lane swizzled LDS read offsets (ky applied via +ky*RSTR, compile-time)
  int vb[T9?12:4];
  if constexpr (T9){
    #pragma unroll
    for (int kx=0;kx<3;kx++)
      #pragma unroll
      for (int pf=0;pf<4;pf++){
        int px = pf*16 + l15 + kx;
        vb[kx*4+pf] = px*64 + ((g4 ^ (px&3))<<4);
      }
  } else {
    #pragma unroll
    for (int pf=0;pf<4;pf++){
      int px = pf*16 + l15;
      vb[pf] = px*64 + ((g4 ^ (px&3))<<4);
    }
  }

  // each wave owns 4 consecutive cb blocks (64 co) -- no A duplication
  const unsigned short* wA = wf + (size_t)(w*4)*(8*TAPS*512) + (size_t)lane*8;

  f32x4 acc0[4][4], acc1[4][4];
  #pragma unroll
  for (int i=0;i<4;i++)
    #pragma unroll
    for (int j=0;j<4;j++){
      acc0[i][j] = (f32x4){0.f,0.f,0.f,0.f};
      acc1[i][j] = (f32x4){0.f,0.f,0.f,0.f};
    }

  // stage current kc into buffer at byte offset jb; advance base one kc (64 B)
  const unsigned short* gbk = gb;
  auto stage = [&](int jb){
    #pragma unroll
    for (int i=0;i<NFULL;i++) gload16(gbk + Poff[i], (char*)&lds[0] + jb + Coff[i]);
    if constexpr (NTAIL > 0){
      if (w < NTAIL) gload16(gbk + Poff[NFULL], (char*)&lds[0] + jb + Coff[NFULL]);
    }
    gbk += 32;
  };

#define LOADB(KY, KX, BV) { \
  _Pragma("unroll") \
  for (int pf=0;pf<4;pf++) BV[pf] = *(const bf16x8*)(base + (KY)*RSTR + vb[(KX)*4+pf]); }

#define LOADA(G, AV) { \
  _Pragma("unroll") \
  for (int cf=0;cf<4;cf++) AV[cf] = *(const bf16x8*)(wk + (size_t)cf*(8*TAPS*512) + (G)*512); }

#define MM(AC, AV, BV) { \
  _Pragma("unroll") for (int cf=0;cf<4;cf++) \
  _Pragma("unroll") for (int pf=0;pf<4;pf++) \
    AC[cf][pf] = __builtin_amdgcn_mfma_f32_16x16x32_bf16(AV[cf], BV[pf], AC[cf][pf], 0,0,0); }

  auto compute = [&](int kc, const char* base){
    const unsigned short* wk = wA + (size_t)kc*(TAPS*512);
    bf16x8 A[4], B0[4], B1[4];
    if constexpr (T9){
      // acc0 (row y0): tap rows 0,1,2 <- staged 0,1,2
      // acc1 (row y0+1): tap rows 0,1,2 <- staged 1,2,3
      #pragma unroll
      for (int kx=0;kx<3;kx++){
        LOADB(0,kx,B0) LOADB(1,kx,B1)
        LOADA(0*3+kx,A) MM(acc0,A,B0) MM(acc1,A,B1)
        LOADB(2,kx,B0)
        LOADA(1*3+kx,A) MM(acc0,A,B1) MM(acc1,A,B0)
        LOADB(3,kx,B1)
        LOADA(2*3+kx,A) MM(acc0,A,B0) MM(acc1,A,B1)
      }
    } else {
      LOADB(0,0,B0) LOADB(1,0,B1)
      LOADA(0,A) MM(acc0,A,B0) MM(acc1,A,B1)
    }
  };

  // prologue: stage kc=0 into buf0
  stage(0);
  __syncthreads();
  #pragma unroll 1
  for (int kt=0; kt<4; ++kt){
    stage(BUFB);                          // odd-kc loads fly under compute
    compute(2*kt, (const char*)&lds[0]);
    __syncthreads();                      // drains staging + guards buf reuse
    if (kt < 3) stage(0);                 // even-kc prefetch
    compute(2*kt+1, (const char*)&lds[0] + BUFB);
    __syncthreads();
  }
#undef LOADB
#undef LOADA
#undef MM

  // epilogue: bias (+BN folded) + ReLU, bf16 NHWC store (2 rows per thread)
  bool ok1 = (y0 + 1) < y_end;
  int oslot = y0 - out_row0;
  unsigned short* ob = outb + ((size_t)b*RBout + oslot)*rowEl + 256; // +1 pad col
  #pragma unroll
  for (int cf=0; cf<4; ++cf){
    int co0 = w*64 + cf*16 + g4*4;
    f32x4 bb = *(const f32x4*)(bias + co0);
    #pragma unroll
    for (int pf=0; pf<4; ++pf){
      int x = x0 + pf*16 + l15;
      if (x < W){
        float v0 = acc0[cf][pf][0]+bb[0], v1 = acc0[cf][pf][1]+bb[1];
        float v2 = acc0[cf][pf][2]+bb[2], v3 = acc0[cf][pf][3]+bb[3];
        if (RELU){ v0=fmaxf(v0,0.f); v1=fmaxf(v1,0.f); v2=fmaxf(v2,0.f); v3=fmaxf(v3,0.f); }
        us4 o = { f2bf(v0), f2bf(v1), f2bf(v2), f2bf(v3) };
        *(us4*)(ob + (size_t)x*256 + co0) = o;
        if (ok1){
          float u0 = acc1[cf][pf][0]+bb[0], u1 = acc1[cf][pf][1]+bb[1];
          float u2 = acc1[cf][pf][2]+bb[2], u3 = acc1[cf][pf][3]+bb[3];
          if (RELU){ u0=fmaxf(u0,0.f); u1=fmaxf(u1,0.f); u2=fmaxf(u2,0.f); u3=fmaxf(u3,0.f); }
          us4 o1 = { f2bf(u0), f2bf(u1), f2bf(u2), f2bf(u3) };
          *(us4*)(ob + rowEl + (size_t)x*256 + co0) = o1;
        }
      }
    }
  }
}

// ---------- pred MFMA: NHWC bf16 -> sectioned NCHW fp32 out ----------
__global__ __launch_bounds__(256) void k_pred_mfma(
    const unsigned short* __restrict__ in, const unsigned short* __restrict__ wfP,
    const float* __restrict__ bp, float* __restrict__ outl,
    int H, int W, int Wp, int y_begin, int in_row0, int RBin)
{
  __shared__ __align__(16) unsigned short Xs[64][40];
  int tid = threadIdx.x;
  int lane = tid&63, w = tid>>6;
  int l15 = lane&15, g4 = lane>>4;
  int x0 = blockIdx.x*64;
  int y = y_begin + blockIdx.y;
  int b = blockIdx.z;
  int slot = y - in_row0;
  const unsigned short* inb = in + (((size_t)b*RBin + slot)*Wp + 1)*256;

  f32x4 acc[3];
  #pragma unroll
  for (int f=0;f<3;f++) acc[f] = (f32x4){0.f,0.f,0.f,0.f};

  for (int kc=0;kc<8;kc++){
    {
      int px = tid>>2, qq = tid&3;
      int xg = x0+px;
      us4 v0={0,0,0,0}, v1={0,0,0,0};
      if (xg < W){
        const unsigned short* src = inb + (size_t)xg*256 + kc*32 + qq*8;
        v0 = *(const us4*)src; v1 = *(const us4*)(src+4);
      }
      unsigned short* d = &Xs[px][qq*8];
      *(us4*)d = v0; *(us4*)(d+4) = v1;
    }
    __syncthreads();
    bf16x8 Bf = *(const bf16x8*)&Xs[w*16 + l15][g4*8];
    #pragma unroll
    for (int f=0;f<3;f++){
      bf16x8 Af = *(const bf16x8*)(wfP + (((size_t)kc*3 + f)*64 + lane)*8);
      acc[f] = __builtin_amdgcn_mfma_f32_16x16x32_bf16(Af, Bf, acc[f], 0,0,0);
    }
    __syncthreads();
  }
  size_t S = (size_t)H*W;
  int px = x0 + w*16 + l15;
  if (px >= W) return;
  #pragma unroll
  for (int f=0;f<3;f++){
    #pragma unroll
    for (int r=0;r<4;r++){
      int co = f*16 + g4*4 + r;
      if (co < 45){
        float val = acc[f][r] + bp[co];
        int a_idx = co/15, c = co%15;
        int cum,c0,n;
        if (c<4)       {cum=0;c0=0;n=4;}
        else if (c==4) {cum=4;c0=4;n=1;}
        else if (c<10) {cum=5;c0=5;n=5;}
        else if (c<14) {cum=10;c0=10;n=4;}
        else           {cum=14;c0=14;n=1;}
        if (c==4) val = 1.f/(1.f+expf(-val));
        else if (c==14) val = (val>20.f? val : log1pf(expf(val))) + 1.f;
        size_t chan = ((size_t)(12*cum) + (size_t)((b*3+a_idx)*n + (c-c0)))*S;
        outl[chan + (size_t)y*W + px] = val;
      }
    }
  }
}

// ---------- host ----------
extern "C" void kernel_launch(void* const* d_in, const int* in_sizes, int n_in,
                              void* d_out, int out_size, void* d_ws, size_t ws_size,
                              hipStream_t stream)
{
  static const int Hs[4] = {192,96,48,24};
  static const int Wd[4] = {320,160,80,40};
  const float* feat[4] = {(const float*)d_in[0],(const float*)d_in[1],
                          (const float*)d_in[2],(const float*)d_in[3]};
  const float* adapt_w = (const float*)d_in[4];
  const float* adapt_b = (const float*)d_in[5];
  const float* w1 = (const float*)d_in[6];  const float* b1 = (const float*)d_in[7];
  const float* g1 = (const float*)d_in[8];  const float* be1= (const float*)d_in[9];
  const float* m1 = (const float*)d_in[10]; const float* v1 = (const float*)d_in[11];
  const float* w2 = (const float*)d_in[12]; const float* b2 = (const float*)d_in[13];
  const float* g2 = (const float*)d_in[14]; const float* be2= (const float*)d_in[15];
  const float* m2 = (const float*)d_in[16]; const float* v2 = (const float*)d_in[17];
  const float* wp = (const float*)d_in[18]; const float* bp = (const float*)d_in[19];
  float* out = (float*)d_out;

  char* base = (char*)d_ws;
  size_t off = 0;
  auto alloc = [&](size_t bytes)->char*{
    char* p = base + off; off = (off + bytes + 255) & ~(size_t)255; return p; };

  const size_t WF3_L = (size_t)16*8*9*512;
  const size_t WFA_L = (size_t)16*8*512;
  const size_t WFP_L = (size_t)8*3*512;
  unsigned short* wf1 = (unsigned short*)alloc(4*WF3_L*2);
  unsigned short* wf2 = (unsigned short*)alloc(4*WF3_L*2);
  unsigned short* wfA = (unsigned short*)alloc(4*WFA_L*2);
  unsigned short* wfP = (unsigned short*)alloc(4*WFP_L*2);
  float* biasc1 = (float*)alloc(1024*4);
  float* biasc2 = (float*)alloc(1024*4);
  char*  bufbase = base + off;
  size_t rem = (ws_size > off + 65536) ? (ws_size - off - 65536) : 0;

  k_repack_conv <<<dim3(1024), dim3(256), 0, stream>>>(w1, g1, v1, wf1);
  k_repack_conv <<<dim3(1024), dim3(256), 0, stream>>>(w2, g2, v2, wf2);
  k_repack_adapt<<<dim3(128),  dim3(256), 0, stream>>>(adapt_w, wfA);
  k_repack_pred <<<dim3(32),   dim3(192), 0, stream>>>(wp, wfP);
  k_bias<<<dim3(4), dim3(256), 0, stream>>>(b1, g1, be1, m1, v1, biasc1);
  k_bias<<<dim3(4), dim3(256), 0, stream>>>(b2, g2, be2, m2, v2, biasc2);

  size_t out_off = 0;
  for (int l=0;l<4;l++){
    int H = Hs[l], W = Wd[l], Wp = W + 2;
    size_t S = (size_t)H*W;
    size_t rowEl = (size_t)Wp*256;            // elements per slot-row (1 batch)
    long slotsAvail = (long)(rem / (rowEl*2));
    long Rl = (slotsAvail - 64) / 12;
    int R = (int)(Rl < 2 ? 2 : (Rl > H ? (long)H : Rl));
    int RBf = R + 4, RB1 = R + 2;
    unsigned short* featT = (unsigned short*)bufbase;      // also conv2 output
    unsigned short* buf0  = featT + ((size_t)4*RBf + 8)*rowEl;
    unsigned short* buf1  = buf0  + ((size_t)4*RBf + 8)*rowEl;
    int nPxT = (W + 63) / 64;
    long zcGrid0 = ((long)4*RBf*2*256 + 2047)/2048;
    long zcGrid1 = ((long)4*RB1*2*256 + 2047)/2048;
    k_zcol<<<dim3((unsigned)zcGrid0), dim3(256), 0, stream>>>(buf0, Wp, RBf, W);
    k_zcol<<<dim3((unsigned)zcGrid1), dim3(256), 0, stream>>>(buf1, Wp, RB1, W);

    for (int r0 = 0; r0 < H; r0 += R){
      int r1 = (r0 + R < H) ? (r0 + R) : H;
      int Rc = r1 - r0;
      int ya0 = (r0-2 < 0) ? 0 : r0-2;
      int ya1 = (r1+2 > H) ? H : r1+2;
      int yb0 = (r0-1 < 0) ? 0 : r0-1;
      int yb1 = (r1+1 > H) ? H : r1+1;

      if (r0 == 0){
        long zg = ((long)4*2*Wp*256 + 2047)/2048;
        k_zrow<<<dim3((unsigned)zg), dim3(256), 0, stream>>>(buf0, (long)RBf*Wp*256, Wp, 0, 2);
        long zg1 = ((long)4*1*Wp*256 + 2047)/2048;
        k_zrow<<<dim3((unsigned)zg1), dim3(256), 0, stream>>>(buf1, (long)RB1*Wp*256, Wp, 0, 1);
      }
      if (r1 == H){
        long zg = ((long)4*2*Wp*256 + 2047)/2048;
        k_zrow<<<dim3((unsigned)zg), dim3(256), 0, stream>>>(buf0, (long)RBf*Wp*256, Wp, Rc+2, 2);
        long zg1 = ((long)4*1*Wp*256 + 2047)/2048;
        k_zrow<<<dim3((unsigned)zg1), dim3(256), 0, stream>>>(buf1, (long)RB1*Wp*256, Wp, Rc+1, 1);
      }

      k_trans<<<dim3(nPxT, ya1-ya0, 4), dim3(256), 0, stream>>>(
          feat[l], featT, H, W, Wp, ya0, ya0-(r0-2), RBf);

      // adapt: featT -> buf0, rows [ya0, ya1)
      k_conv5<1,false><<<dim3(nPxT, (ya1-ya0+1)/2, 4), dim3(256), 0, stream>>>(
          featT, wfA + (size_t)l*WFA_L, adapt_b + l*256, buf0,
          W, Wp, ya0, ya1, r0-2, RBf, r0-2, RBf);

      // conv1: buf0 -> buf1, rows [yb0, yb1)
      k_conv5<9,true><<<dim3(nPxT, (yb1-yb0+1)/2, 4), dim3(256), 0, stream>>>(
          buf0, wf1 + (size_t)l*WF3_L, biasc1 + l*256, buf1,
          W, Wp, yb0, yb1, r0-2, RBf, r0-1, RB1);

      // conv2: buf1 -> featT, rows [r0, r1)
      k_conv5<9,true><<<dim3(nPxT, (Rc+1)/2, 4), dim3(256), 0, stream>>>(
          buf1, wf2 + (size_t)l*WF3_L, biasc2 + l*256, featT,
          W, Wp, r0, r1, r0-1, RB1, r0, RBf);

      k_pred_mfma<<<dim3(nPxT, Rc, 4), dim3(256), 0, stream>>>(
          featT, wfP + (size_t)l*WFP_L, bp + l*45, out + out_off,
          H, W, Wp, r0, r0, RBf);
    }
    out_off += (size_t)4*45*S;
  }
}